// Round 10
// baseline (703.092 us; speedup 1.0000x reference)
//
#include <hip/hip_runtime.h>
#include <math.h>

#define B_ 32
#define T_ 512
#define D_ 768
#define S_ 64
#define C_ 16
#define INV_SQRT_D 0.03608439182435161f
#define SCORE_CLIP_ 20.0f
#define MROW 776   // Mb LDS row length (ushorts): 768 + 8 pad -> 2-way banks
#define WROW 264   // W LDS row length (ushorts): 256 + 8 pad

typedef __attribute__((ext_vector_type(8))) short short8;
typedef __attribute__((ext_vector_type(4))) float f32x4;

// RNE float->bf16
static __device__ __forceinline__ unsigned short f2bf(float f) {
    union { float f; unsigned u; } v; v.f = f;
    unsigned r = v.u + 0x7fffu + ((v.u >> 16) & 1u);
    return (unsigned short)(r >> 16);
}
static __device__ __forceinline__ unsigned pk2(float a, float b) {
    return (unsigned)f2bf(a) | ((unsigned)f2bf(b) << 16);
}
static __device__ __forceinline__ float bf2f(unsigned short h) {
    union { unsigned u; float f; } v; v.u = ((unsigned)h) << 16; return v.f;
}
static __device__ __forceinline__ f32x4 mfma16(short8 a, short8 b, f32x4 c) {
    return __builtin_amdgcn_mfma_f32_16x16x32_bf16(a, b, c, 0, 0, 0);
}

// ---------------------------------------------------------------------------
// Wtv[n][k] = bf16(Wv[k][n])
__global__ __launch_bounds__(256) void k_prep(
    const float* __restrict__ Wv, unsigned short* __restrict__ Wtv)
{
    const int flat = blockIdx.x * 256 + threadIdx.x;   // n*768 + k
    const int n = flat / 768, k = flat - n * 768;
    Wtv[flat] = f2bf(Wv[(size_t)k * D_ + n]);
}

// ---------------------------------------------------------------------------
// Wqkt[n][k] = sum_j Wq[k][j] * Wk[n][j]  (= (Wq@Wk^T)[k][n], stored k-contig)
__global__ __launch_bounds__(256) void k_wqk(
    const float* __restrict__ Wq, const float* __restrict__ Wk,
    unsigned short* __restrict__ Wqkt)
{
    __shared__ unsigned short sA[64][40];   // Wk rows (n)
    __shared__ unsigned short sB[64][40];   // Wq rows (k = output col)
    const int tid = threadIdx.x;
    const int n0 = blockIdx.x * 64;
    const int c0 = blockIdx.y * 64;
    const int lane = tid & 63, w = tid >> 6;
    const int wm = w >> 1, wn = w & 1;
    const int q = lane >> 4, lr = lane & 15;
    const int row = tid >> 2, ch = tid & 3;
    f32x4 acc[2][2];
    #pragma unroll
    for (int i = 0; i < 2; ++i)
        #pragma unroll
        for (int j = 0; j < 2; ++j) acc[i][j] = (f32x4){0.f, 0.f, 0.f, 0.f};
    for (int j0 = 0; j0 < D_; j0 += 32) {
        __syncthreads();
        {
            const float* sa = Wk + (size_t)(n0 + row) * D_ + j0 + ch * 8;
            const float4 x0 = *(const float4*)sa, x1 = *(const float4*)(sa + 4);
            uint4 u;
            u.x = pk2(x0.x, x0.y); u.y = pk2(x0.z, x0.w);
            u.z = pk2(x1.x, x1.y); u.w = pk2(x1.z, x1.w);
            *(uint4*)&sA[row][ch * 8] = u;
            const float* sb = Wq + (size_t)(c0 + row) * D_ + j0 + ch * 8;
            const float4 y0 = *(const float4*)sb, y1 = *(const float4*)(sb + 4);
            uint4 v;
            v.x = pk2(y0.x, y0.y); v.y = pk2(y0.z, y0.w);
            v.z = pk2(y1.x, y1.y); v.w = pk2(y1.z, y1.w);
            *(uint4*)&sB[row][ch * 8] = v;
        }
        __syncthreads();
        short8 a[2], bb[2];
        #pragma unroll
        for (int i = 0; i < 2; ++i) {
            a[i]  = *(const short8*)&sA[wm * 32 + i * 16 + lr][q * 8];
            bb[i] = *(const short8*)&sB[wn * 32 + i * 16 + lr][q * 8];
        }
        #pragma unroll
        for (int i = 0; i < 2; ++i)
            #pragma unroll
            for (int j = 0; j < 2; ++j)
                acc[i][j] = mfma16(a[i], bb[j], acc[i][j]);
    }
    #pragma unroll
    for (int i = 0; i < 2; ++i)
        #pragma unroll
        for (int j = 0; j < 2; ++j)
            #pragma unroll
            for (int r = 0; r < 4; ++r) {
                const int n = n0 + wm * 32 + i * 16 + 4 * q + r;
                const int k = c0 + wn * 32 + j * 16 + lr;
                Wqkt[(size_t)n * D_ + k] = f2bf(acc[i][j][r]);
            }
}

// ---------------------------------------------------------------------------
// X[r][d] = bf16(tok_emb[ids[r]][d] + pos_emb[r%512][d])
__global__ __launch_bounds__(256) void k_embed_x(
    const int* __restrict__ ids, const float* __restrict__ tok_emb,
    const float* __restrict__ pos_emb, unsigned short* __restrict__ Xb)
{
    const int idx = blockIdx.x * 256 + threadIdx.x;      // chunk of 8 elems
    const int r = idx / 96, c = (idx - r * 96) * 8;
    const int id = ids[r], tp = r & (T_ - 1);
    const float* te = tok_emb + (size_t)id * D_ + c;
    const float* pe = pos_emb + (size_t)tp * D_ + c;
    const float4 a0 = *(const float4*)te, a1 = *(const float4*)(te + 4);
    const float4 p0 = *(const float4*)pe, p1 = *(const float4*)(pe + 4);
    uint4 u;
    u.x = pk2(a0.x + p0.x, a0.y + p0.y);
    u.y = pk2(a0.z + p0.z, a0.w + p0.w);
    u.z = pk2(a1.x + p1.x, a1.y + p1.y);
    u.w = pk2(a1.z + p1.z, a1.w + p1.w);
    *(uint4*)(Xb + (size_t)idx * 8) = u;
}

// ---------------------------------------------------------------------------
// Dual GEMM: QK[t][n] = X@Wqkt (natural), Vtt[b][d][t] = (X@Wv)^T. 128x128 tile.
__global__ __launch_bounds__(256) void k_qv(
    const unsigned short* __restrict__ Xb, const unsigned short* __restrict__ Wqkt,
    const unsigned short* __restrict__ Wtv, unsigned short* __restrict__ QK,
    unsigned short* __restrict__ Vtt)
{
    __shared__ unsigned short sX[128][40];
    __shared__ unsigned short sQ[128][40];
    __shared__ unsigned short sV[128][40];
    const int tid = threadIdx.x;
    const int row0 = blockIdx.x * 128;   // token rows
    const int col0 = blockIdx.y * 128;   // n cols
    const int lane = tid & 63, w = tid >> 6;
    const int wm = w >> 1, wn = w & 1;
    const int q = lane >> 4, lr = lane & 15;
    f32x4 accq[4][4], accv[4][4];
    #pragma unroll
    for (int i = 0; i < 4; ++i)
        #pragma unroll
        for (int j = 0; j < 4; ++j) {
            accq[i][j] = (f32x4){0.f, 0.f, 0.f, 0.f};
            accv[i][j] = (f32x4){0.f, 0.f, 0.f, 0.f};
        }
    for (int k0 = 0; k0 < D_; k0 += 32) {
        __syncthreads();
        #pragma unroll
        for (int cc = 0; cc < 2; ++cc) {
            const int c = tid + cc * 256;
            const int row = c >> 2, ch = c & 3;
            *(uint4*)&sX[row][ch * 8] =
                *(const uint4*)(Xb + (size_t)(row0 + row) * D_ + k0 + ch * 8);
            *(uint4*)&sQ[row][ch * 8] =
                *(const uint4*)(Wqkt + (size_t)(col0 + row) * D_ + k0 + ch * 8);
            *(uint4*)&sV[row][ch * 8] =
                *(const uint4*)(Wtv + (size_t)(col0 + row) * D_ + k0 + ch * 8);
        }
        __syncthreads();
        short8 a[4], bq[4], bv[4];
        #pragma unroll
        for (int i = 0; i < 4; ++i) {
            a[i]  = *(const short8*)&sX[wm * 64 + i * 16 + lr][q * 8];
            bq[i] = *(const short8*)&sQ[wn * 64 + i * 16 + lr][q * 8];
            bv[i] = *(const short8*)&sV[wn * 64 + i * 16 + lr][q * 8];
        }
        #pragma unroll
        for (int i = 0; i < 4; ++i)
            #pragma unroll
            for (int j = 0; j < 4; ++j) {
                accq[i][j] = mfma16(a[i], bq[j], accq[i][j]);
                accv[i][j] = mfma16(a[i], bv[j], accv[i][j]);
            }
    }
    const int b = row0 >> 9;
    #pragma unroll
    for (int i = 0; i < 4; ++i)
        #pragma unroll
        for (int j = 0; j < 4; ++j) {
            const int gr = row0 + wm * 64 + i * 16 + 4 * q;   // token row
            const int gc = col0 + wn * 64 + j * 16 + lr;      // n col
            #pragma unroll
            for (int r = 0; r < 4; ++r)
                QK[(size_t)(gr + r) * D_ + gc] = f2bf(accq[i][j][r]);
            uint2 u;
            u.x = pk2(accv[i][j][0], accv[i][j][1]);
            u.y = pk2(accv[i][j][2], accv[i][j][3]);
            const int t = (gr & (T_ - 1));
            *(uint2*)(Vtt + ((size_t)b * D_ + gc) * T_ + t) = u;
        }
}

// ---------------------------------------------------------------------------
// Fused recurrence: one workgroup per batch element, 16 waves.
// M fp32 lives in MFMA accumulator registers; bf16 shadow in LDS; W staged in
// LDS in two t-halves. 4 update steps + final scores -> Wbar; writes Mm fp32.
// Fragment conventions identical to the verified round-5 kernels:
//   operands: row/col = lane&15, k = (lane>>4)*8 + e (k-contig LDS/global)
//   C/D: col = lane&15, row = 4*(lane>>4) + reg
__global__ __launch_bounds__(1024, 4) void k_loop(
    const unsigned short* __restrict__ QK,
    const unsigned short* __restrict__ Vtt,
    const float* __restrict__ mem_init,
    const int* __restrict__ amask,
    float* __restrict__ Mm, float* __restrict__ Wbar)
{
    __shared__ unsigned short Mb[S_][MROW];   // 99328 B
    __shared__ unsigned short Wl[S_][WROW];   // 33792 B  (reused as f32 scratch)
    const int b = blockIdx.x;
    const int tid = threadIdx.x;
    const int w = tid >> 6;            // wave 0..15
    const int lane = tid & 63;
    const int q = lane >> 4, c = lane & 15;
    const int d0 = w * 48;             // this wave's 48 d-columns (write GEMM rows)

    // ---- init: M registers + bf16 shadow ----
    // Macc[i][j][r] holds M[s = j*16+c][d = d0 + i*16 + 4q + r]
    f32x4 Macc[3][4];
    #pragma unroll
    for (int i = 0; i < 3; ++i)
        #pragma unroll
        for (int j = 0; j < 4; ++j) {
            f32x4 v;
            #pragma unroll
            for (int r = 0; r < 4; ++r)
                v[r] = mem_init[(size_t)(j * 16 + c) * D_ + d0 + i * 16 + 4 * q + r];
            Macc[i][j] = v;
            #pragma unroll
            for (int r = 0; r < 4; ++r)
                Mb[j * 16 + c][d0 + i * 16 + 4 * q + r] = f2bf(v[r]);
        }
    // mask rows for this thread's 8 t values: t = w*32 + ti*16 + 4q + r
    float mrow[2][4];
    #pragma unroll
    for (int ti = 0; ti < 2; ++ti)
        #pragma unroll
        for (int r = 0; r < 4; ++r)
            mrow[ti][r] = (amask[b * T_ + w * 32 + ti * 16 + 4 * q + r] > 0) ? 1.f : 0.f;
    __syncthreads();

    unsigned wv[2][4][2];   // softmax'd W, bf16-packed: [ti][r][pair(j01,j23)]

    for (int step = 0; step < 5; ++step) {
        // ---- scores + in-register softmax (two 16-row sub-passes) ----
        #pragma unroll
        for (int ti = 0; ti < 2; ++ti) {
            f32x4 s0 = {0.f,0.f,0.f,0.f}, s1 = {0.f,0.f,0.f,0.f};
            f32x4 s2 = {0.f,0.f,0.f,0.f}, s3 = {0.f,0.f,0.f,0.f};
            const unsigned short* qp =
                QK + ((size_t)b * T_ + w * 32 + ti * 16 + c) * D_ + q * 8;
            #pragma unroll 4
            for (int k0 = 0; k0 < D_; k0 += 32) {
                const short8 a = *(const short8*)(qp + k0);
                s0 = mfma16(a, *(const short8*)&Mb[ 0 + c][k0 + q * 8], s0);
                s1 = mfma16(a, *(const short8*)&Mb[16 + c][k0 + q * 8], s1);
                s2 = mfma16(a, *(const short8*)&Mb[32 + c][k0 + q * 8], s2);
                s3 = mfma16(a, *(const short8*)&Mb[48 + c][k0 + q * 8], s3);
            }
            #pragma unroll
            for (int r = 0; r < 4; ++r) {
                float v0 = fminf(fmaxf(s0[r] * INV_SQRT_D, -SCORE_CLIP_), SCORE_CLIP_);
                float v1 = fminf(fmaxf(s1[r] * INV_SQRT_D, -SCORE_CLIP_), SCORE_CLIP_);
                float v2 = fminf(fmaxf(s2[r] * INV_SQRT_D, -SCORE_CLIP_), SCORE_CLIP_);
                float v3 = fminf(fmaxf(s3[r] * INV_SQRT_D, -SCORE_CLIP_), SCORE_CLIP_);
                float mx = fmaxf(fmaxf(v0, v1), fmaxf(v2, v3));
                mx = fmaxf(mx, __shfl_xor(mx, 1));
                mx = fmaxf(mx, __shfl_xor(mx, 2));
                mx = fmaxf(mx, __shfl_xor(mx, 4));
                mx = fmaxf(mx, __shfl_xor(mx, 8));
                v0 = expf(v0 - mx); v1 = expf(v1 - mx);
                v2 = expf(v2 - mx); v3 = expf(v3 - mx);
                float sum = v0 + v1 + v2 + v3;
                sum += __shfl_xor(sum, 1);
                sum += __shfl_xor(sum, 2);
                sum += __shfl_xor(sum, 4);
                sum += __shfl_xor(sum, 8);
                const float inv = mrow[ti][r] / sum;
                wv[ti][r][0] = pk2(v0 * inv, v1 * inv);
                wv[ti][r][1] = pk2(v2 * inv, v3 * inv);
            }
        }
        if (step == 4) break;

        // ---- write GEMM: seed C with 9*M, accumulate W^T@V over two t-halves
        #pragma unroll
        for (int i = 0; i < 3; ++i)
            #pragma unroll
            for (int j = 0; j < 4; ++j)
                #pragma unroll
                for (int r = 0; r < 4; ++r)
                    Macc[i][j][r] *= 9.0f;

        #pragma unroll
        for (int h = 0; h < 2; ++h) {
            __syncthreads();                     // prev Wl reads / scores done
            if ((w >> 3) == h) {                 // waves owning this t-half stage
                #pragma unroll
                for (int ti = 0; ti < 2; ++ti)
                    #pragma unroll
                    for (int r = 0; r < 4; ++r) {
                        const int t = (w & 7) * 32 + ti * 16 + 4 * q + r;
                        Wl[ 0 + c][t] = (unsigned short)(wv[ti][r][0] & 0xffffu);
                        Wl[16 + c][t] = (unsigned short)(wv[ti][r][0] >> 16);
                        Wl[32 + c][t] = (unsigned short)(wv[ti][r][1] & 0xffffu);
                        Wl[48 + c][t] = (unsigned short)(wv[ti][r][1] >> 16);
                    }
            }
            __syncthreads();
            const unsigned short* vp =
                Vtt + ((size_t)b * D_ + d0 + c) * T_ + h * 256 + q * 8;
            #pragma unroll 2
            for (int k0 = 0; k0 < 256; k0 += 32) {
                const short8 a0 = *(const short8*)(vp + k0);
                const short8 a1 = *(const short8*)(vp + 16 * T_ + k0);
                const short8 a2 = *(const short8*)(vp + 32 * T_ + k0);
                #pragma unroll
                for (int j = 0; j < 4; ++j) {
                    const short8 bb = *(const short8*)&Wl[j * 16 + c][k0 + q * 8];
                    Macc[0][j] = mfma16(a0, bb, Macc[0][j]);
                    Macc[1][j] = mfma16(a1, bb, Macc[1][j]);
                    Macc[2][j] = mfma16(a2, bb, Macc[2][j]);
                }
            }
        }
        // M = clip(0.1*(9M + write)) ; refresh bf16 shadow
        #pragma unroll
        for (int i = 0; i < 3; ++i)
            #pragma unroll
            for (int j = 0; j < 4; ++j)
                #pragma unroll
                for (int r = 0; r < 4; ++r)
                    Macc[i][j][r] = fminf(fmaxf(0.1f * Macc[i][j][r], -50.f), 50.f);
        __syncthreads();
        #pragma unroll
        for (int i = 0; i < 3; ++i)
            #pragma unroll
            for (int j = 0; j < 4; ++j)
                #pragma unroll
                for (int r = 0; r < 4; ++r)
                    Mb[j * 16 + c][d0 + i * 16 + 4 * q + r] = f2bf(Macc[i][j][r]);
        __syncthreads();
    }

    // ---- Wbar = column-mean of final W / valid ----
    float ps0 = 0.f, ps1 = 0.f, ps2 = 0.f, ps3 = 0.f;
    #pragma unroll
    for (int ti = 0; ti < 2; ++ti)
        #pragma unroll
        for (int r = 0; r < 4; ++r) {
            ps0 += bf2f((unsigned short)(wv[ti][r][0] & 0xffffu));
            ps1 += bf2f((unsigned short)(wv[ti][r][0] >> 16));
            ps2 += bf2f((unsigned short)(wv[ti][r][1] & 0xffffu));
            ps3 += bf2f((unsigned short)(wv[ti][r][1] >> 16));
        }
    ps0 += __shfl_xor(ps0, 16); ps0 += __shfl_xor(ps0, 32);
    ps1 += __shfl_xor(ps1, 16); ps1 += __shfl_xor(ps1, 32);
    ps2 += __shfl_xor(ps2, 16); ps2 += __shfl_xor(ps2, 32);
    ps3 += __shfl_xor(ps3, 16); ps3 += __shfl_xor(ps3, 32);
    float vloc = 0.f;
    if (c == 0) {
        #pragma unroll
        for (int ti = 0; ti < 2; ++ti)
            #pragma unroll
            for (int r = 0; r < 4; ++r) vloc += mrow[ti][r];
    }
    #pragma unroll
    for (int o = 1; o < 64; o <<= 1) vloc += __shfl_xor(vloc, o);

    float* scr = (float*)&Wl[0][0];
    __syncthreads();
    if (lane < 16) {            // q==0 lanes hold the reduced sums
        scr[w * 64 +  0 + c] = ps0;
        scr[w * 64 + 16 + c] = ps1;
        scr[w * 64 + 32 + c] = ps2;
        scr[w * 64 + 48 + c] = ps3;
    }
    if (lane == 0) scr[1024 + w] = vloc;
    __syncthreads();
    if (tid == 0) {
        float vv = 0.f;
        #pragma unroll
        for (int ww = 0; ww < 16; ++ww) vv += scr[1024 + ww];
        scr[1040] = vv;
    }
    __syncthreads();
    if (tid < 64) {
        float s = 0.f;
        #pragma unroll
        for (int ww = 0; ww < 16; ++ww) s += scr[ww * 64 + tid];
        Wbar[b * S_ + tid] = s / fmaxf(scr[1040], 1.0f);
    }
    // ---- write fp32 M out for the head ----
    #pragma unroll
    for (int i = 0; i < 3; ++i)
        #pragma unroll
        for (int j = 0; j < 4; ++j)
            #pragma unroll
            for (int r = 0; r < 4; ++r)
                Mm[((size_t)b * S_ + j * 16 + c) * D_ + d0 + i * 16 + 4 * q + r] =
                    Macc[i][j][r];
}

// ---------------------------------------------------------------------------
// pooled = Wbar @ M; LN; logits = pooled @ cls_w + cls_b; nan_to_num
__global__ __launch_bounds__(256) void k_head(
    const float* __restrict__ Wbar, const float* __restrict__ Mm,
    const float* __restrict__ ln_scale, const float* __restrict__ ln_bias,
    const float* __restrict__ cls_w, const float* __restrict__ cls_b,
    float* __restrict__ out)
{
    __shared__ float sw[64];
    __shared__ float sp[768];
    __shared__ float sred[4];
    __shared__ float sl[16][17];
    const int b = blockIdx.x, tid = threadIdx.x;
    if (tid < 64) sw[tid] = Wbar[b * S_ + tid];
    __syncthreads();
    float p[3] = {0.f, 0.f, 0.f};
    const float* Mbp = Mm + (size_t)b * S_ * D_;
    for (int s = 0; s < S_; ++s) {
        const float wvv = sw[s];
        const float* Mr = Mbp + (size_t)s * D_;
        #pragma unroll
        for (int jj = 0; jj < 3; ++jj)
            p[jj] = fmaf(wvv, Mr[tid + (jj << 8)], p[jj]);
    }
    float lsum = p[0] + p[1] + p[2];
    #pragma unroll
    for (int o = 1; o < 64; o <<= 1) lsum += __shfl_xor(lsum, o);
    if ((tid & 63) == 0) sred[tid >> 6] = lsum;
    __syncthreads();
    const float mean = (sred[0] + sred[1] + sred[2] + sred[3]) * (1.0f / 768.0f);
    float lv = 0.f;
    #pragma unroll
    for (int jj = 0; jj < 3; ++jj) { const float d = p[jj] - mean; lv += d * d; }
    #pragma unroll
    for (int o = 1; o < 64; o <<= 1) lv += __shfl_xor(lv, o);
    __syncthreads();
    if ((tid & 63) == 0) sred[tid >> 6] = lv;
    __syncthreads();
    const float var = (sred[0] + sred[1] + sred[2] + sred[3]) * (1.0f / 768.0f);
    const float inv = 1.0f / sqrtf(var + 1e-5f);
    #pragma unroll
    for (int jj = 0; jj < 3; ++jj) {
        const int d = tid + (jj << 8);
        sp[d] = (p[jj] - mean) * inv * ln_scale[d] + ln_bias[d];
    }
    __syncthreads();
    const int cc = tid & 15, g = tid >> 4;
    float part = 0.f;
    const int dd0 = g * 48;
    for (int d = dd0; d < dd0 + 48; ++d)
        part = fmaf(sp[d], cls_w[(size_t)d * C_ + cc], part);
    sl[g][cc] = part;
    __syncthreads();
    if (tid < 16) {
        float sum = cls_b[tid];
        #pragma unroll
        for (int g2 = 0; g2 < 16; ++g2) sum += sl[g2][tid];
        if (isnan(sum) || isinf(sum)) sum = 0.f;
        out[b * C_ + tid] = sum;
    }
}

// ---------------------------------------------------------------------------
extern "C" void kernel_launch(void* const* d_in, const int* in_sizes, int n_in,
                              void* d_out, int out_size, void* d_ws, size_t ws_size,
                              hipStream_t stream) {
    (void)in_sizes; (void)n_in; (void)out_size; (void)ws_size;
    const int*   ids      = (const int*)d_in[0];
    const int*   amask    = (const int*)d_in[1];
    const float* tok_emb  = (const float*)d_in[2];
    const float* pos_emb  = (const float*)d_in[3];
    const float* Wq       = (const float*)d_in[4];
    const float* Wk       = (const float*)d_in[5];
    const float* Wv       = (const float*)d_in[6];
    const float* mem_init = (const float*)d_in[7];
    const float* ln_scale = (const float*)d_in[8];
    const float* ln_bias  = (const float*)d_in[9];
    const float* cls_w    = (const float*)d_in[10];
    const float* cls_b    = (const float*)d_in[11];

    char* base = (char*)d_ws;
    unsigned short* Xb   = (unsigned short*)base;   base += (size_t)B_ * T_ * D_ * 2;
    unsigned short* Wtv  = (unsigned short*)base;   base += (size_t)D_ * D_ * 2;
    unsigned short* Wqkt = (unsigned short*)base;   base += (size_t)D_ * D_ * 2;
    unsigned short* QK   = (unsigned short*)base;   base += (size_t)B_ * T_ * D_ * 2;
    unsigned short* Vtt  = (unsigned short*)base;   base += (size_t)B_ * D_ * T_ * 2;
    float*          Mm   = (float*)base;            base += (size_t)B_ * S_ * D_ * 4;
    float*          Wbar = (float*)base;            base += (size_t)B_ * S_ * 4;

    k_prep<<<D_ * D_ / 256, 256, 0, stream>>>(Wv, Wtv);
    k_wqk<<<dim3(D_ / 64, D_ / 64), 256, 0, stream>>>(Wq, Wk, Wqkt);
    k_embed_x<<<B_ * T_ * D_ / 8 / 256, 256, 0, stream>>>(ids, tok_emb, pos_emb, Xb);
    k_qv<<<dim3(B_ * T_ / 128, D_ / 128), 256, 0, stream>>>(Xb, Wqkt, Wtv, QK, Vtt);
    k_loop<<<B_, 1024, 0, stream>>>(QK, Vtt, mem_init, amask, Mm, Wbar);
    k_head<<<B_, 256, 0, stream>>>(Wbar, Mm, ln_scale, ln_bias, cls_w, cls_b,
                                   (float*)d_out);
}